// Round 3
// baseline (276.964 us; speedup 1.0000x reference)
//
#include <hip/hip_runtime.h>
#include <hip/hip_bf16.h>

// TMDConv (PaiNN/TorchMD-style) two-pass message passing on MI355X.
// R2 changes vs R1:
//  - All gathered payloads (phi, v, vnew, s2) are bf16, packed per-feature as
//    ushort4 {t0,t1,t2,pad} -> ONE 8B aligned load per edge-lane per tensor.
//  - mv_w -> padded scale-folded fp32 table mvp[384][24] (bias at slot 20),
//    held in a true VGPR array (launch_bounds(256,4) -> ~128 VGPR budget).
//  - pass1/pass2: block = 1 node, 4 waves = (feature half) x (edge parity),
//    LDS reduction of partial accumulators -> 2x wave parallelism.

#define F_DIM   128
#define F3_DIM  384
#define L_DIM   20
#define CAP     64          // max in-degree bucket capacity

typedef __attribute__((ext_vector_type(8))) short short8;
typedef __attribute__((ext_vector_type(4))) float f32x4;
typedef __attribute__((ext_vector_type(4))) unsigned short us4;

__device__ __forceinline__ unsigned short f2bf(float f) {
  union { float f; unsigned u; } a; a.f = f;
  unsigned u = a.u;
  u = (u + 0x7FFFu + ((u >> 16) & 1u)) >> 16;   // RNE
  return (unsigned short)u;
}
__device__ __forceinline__ float bf2f(unsigned short u) {
  union { unsigned u; float f; } a; a.u = ((unsigned)u) << 16;
  return a.f;
}

// ---------------------------------------------------------------------------
// one fused cast kernel: 4 weight matrices -> bf16, s -> bf16, v -> us4 bf16,
// mv_w -> mvp[384][24] fp32 (x sqrt(2/5), bias at col 20, cols 21..23 = 0)
__global__ __launch_bounds__(256) void cast_kernel(
    const float* __restrict__ ms1_w, unsigned short* __restrict__ w_ms1,
    const float* __restrict__ ms2_w, unsigned short* __restrict__ w_ms2,
    const float* __restrict__ us1_w, unsigned short* __restrict__ w_us1,
    const float* __restrict__ us2_w, unsigned short* __restrict__ w_us2,
    const float* __restrict__ s,     unsigned short* __restrict__ sbf,
    const float* __restrict__ v,     us4* __restrict__ v4,
    const float* __restrict__ mv_w,  const float* __restrict__ mv_b,
    float* __restrict__ mvp, int nF)                 // nF = N*128
{
  int i = blockIdx.x * 256 + threadIdx.x;
  if (i < 16384) w_ms1[i] = f2bf(ms1_w[i]);
  if (i < 49152) w_ms2[i] = f2bf(ms2_w[i]);
  if (i < 16384) w_us1[i] = f2bf(us1_w[i]);
  if (i < 49152) w_us2[i] = f2bf(us2_w[i]);
  if (i < nF)    sbf[i] = f2bf(s[i]);
  if (i < nF) {
    const float* vp = v + (size_t)i * 3;
    us4 o; o.x = f2bf(vp[0]); o.y = f2bf(vp[1]); o.z = f2bf(vp[2]); o.w = 0;
    v4[i] = o;
  }
  if (i < 384 * 24) {
    int o = i / 24, col = i - o * 24;
    float val = 0.f;
    if (col < 20)       val = mv_w[o * 20 + col] * 0.6324555320336759f; // sqrt(2/5)
    else if (col == 20) val = mv_b[o];
    mvp[i] = val;
  }
}

// ---------------------------------------------------------------------------
// bucketed CSR fill: ebuf[d*CAP + p] = src; cursor[d] ends equal to deg[d]
__global__ __launch_bounds__(256) void fill_kernel(
    const int* __restrict__ src, const int* __restrict__ dst,
    int* __restrict__ cursor, int* __restrict__ ebuf, int E)
{
  int e = blockIdx.x * 256 + threadIdx.x;
  if (e < E) {
    int d = dst[e];
    int p = atomicAdd(&cursor[d], 1);
    if (p < CAP) ebuf[d * CAP + p] = src[e];
  }
}

// ---------------------------------------------------------------------------
// Yp[n][128][4] (bf16, slot t = col t*128+f) = ssp(X @ W1^T + b1) @ W2^T + b2
// one wave per block, 16 nodes per block.
__global__ __launch_bounds__(64) void mlp_kernel(
    const unsigned short* __restrict__ X,    // [n][128] bf16
    const unsigned short* __restrict__ W1,   // [128][128] bf16
    const float* __restrict__ B1,            // [128]
    const unsigned short* __restrict__ W2,   // [384][128] bf16
    const float* __restrict__ B2,            // [384]
    unsigned short* __restrict__ Yp)         // [n][128][4] bf16 packed
{
  __shared__ float HT[128 * 17];
  const int lane = threadIdx.x;
  const int c    = lane & 15;
  const int quad = lane >> 4;
  const int m0   = blockIdx.x * 16;

  f32x4 acc[8];
#pragma unroll
  for (int t = 0; t < 8; t++) acc[t] = (f32x4){0.f, 0.f, 0.f, 0.f};
#pragma unroll
  for (int kk = 0; kk < 4; kk++) {
    short8 a = *(const short8*)(X + (size_t)(m0 + c) * 128 + kk * 32 + quad * 8);
#pragma unroll
    for (int t = 0; t < 8; t++) {
      short8 b = *(const short8*)(W1 + (size_t)(t * 16 + c) * 128 + kk * 32 + quad * 8);
      acc[t] = __builtin_amdgcn_mfma_f32_16x16x32_bf16(a, b, acc[t], 0, 0, 0);
    }
  }
#pragma unroll
  for (int t = 0; t < 8; t++) {
    float bias = B1[t * 16 + c];
    int k = t * 16 + c;
#pragma unroll
    for (int r = 0; r < 4; r++) {
      float h = acc[t][r] + bias;
      float sp = (h > 15.f) ? h : log1pf(__expf(h));
      sp -= 0.69314718056f;
      HT[k * 17 + quad * 4 + r] = sp;
    }
  }
  __syncthreads();

  for (int g = 0; g < 3; g++) {
    f32x4 acc2[8];
#pragma unroll
    for (int t = 0; t < 8; t++) acc2[t] = (f32x4){0.f, 0.f, 0.f, 0.f};
#pragma unroll
    for (int kk = 0; kk < 4; kk++) {
      short8 afr;
#pragma unroll
      for (int j = 0; j < 8; j++) {
        float hv = HT[(kk * 32 + quad * 8 + j) * 17 + c];
        afr[j] = (short)f2bf(hv);
      }
#pragma unroll
      for (int t = 0; t < 8; t++) {
        short8 b = *(const short8*)(W2 + (size_t)(g * 128 + t * 16 + c) * 128 + kk * 32 + quad * 8);
        acc2[t] = __builtin_amdgcn_mfma_f32_16x16x32_bf16(afr, b, acc2[t], 0, 0, 0);
      }
    }
#pragma unroll
    for (int t = 0; t < 8; t++) {
      int f = t * 16 + c;                    // feature in [0,128)
      float bias = B2[g * 128 + f];
#pragma unroll
      for (int r = 0; r < 4; r++) {
        int m = quad * 4 + r;
        Yp[(size_t)(m0 + m) * 512 + f * 4 + g] = f2bf(acc2[t][r] + bias);
      }
    }
  }
}

// ---------------------------------------------------------------------------
// pass 1: block = 1 dst node, 4 waves = (feature half) x (edge parity).
__global__ __launch_bounds__(256, 4) void pass1_kernel(
    const float* __restrict__ x,       // [N,3]
    const us4*  __restrict__ v4,       // [N,128] bf16 packed {vx,vy,vz,_}
    const float* __restrict__ v,       // [N,128,3] fp32 (epilogue add)
    const float* __restrict__ s,       // [N,128]
    const us4*  __restrict__ phi4,     // [N,128] bf16 packed {t0,t1,t2,_}
    const float* __restrict__ mvp,     // [384,24] scale-folded, bias@20
    const int* __restrict__ ebuf,      // [N,CAP]
    const int* __restrict__ deg,
    float* __restrict__ vnew, us4* __restrict__ vnew4,
    float* __restrict__ snew, unsigned short* __restrict__ snew_bf, int nNodes)
{
  __shared__ float red[512];
  const int wave = threadIdx.x >> 6, lane = threadIdx.x & 63;
  const int half = wave >> 1, split = wave & 1;
  const int i = blockIdx.x;
  const int f = lane + 64 * half;       // feature in [0,128)

  // per-lane weight rows in registers (3 x 21 floats, scale folded, bias@20)
  float mvw[3][21];
#pragma unroll
  for (int t = 0; t < 3; t++) {
    const float* row = mvp + (size_t)(t * 128 + f) * 24;
#pragma unroll
    for (int l = 0; l < 21; l++) mvw[t][l] = row[l];
  }

  int cnt = deg[i]; if (cnt > CAP) cnt = CAP;
  const int base = i * CAP;

  // lane-parallel prefetch of edge indices + source coordinates
  int jv = (lane < cnt) ? ebuf[base + lane] : 0;
  float pxa = 0.f, pxb = 0.f, pxc = 0.f;
  if (lane < cnt) {
    pxa = x[jv * 3]; pxb = x[jv * 3 + 1]; pxc = x[jv * 3 + 2];
  }

  const float xi0 = x[i * 3], xi1 = x[i * 3 + 1], xi2 = x[i * 3 + 2];
  float accV0 = 0.f, accV1 = 0.f, accV2 = 0.f, accS = 0.f;

#pragma unroll 2
  for (int e = split; e < cnt; e += 2) {
    int   j  = __shfl(jv, e);
    float a0 = __shfl(pxa, e), a1 = __shfl(pxb, e), a2 = __shfl(pxc, e);
    float d0 = a0 - xi0, d1 = a1 - xi1, d2 = a2 - xi2;
    float r2 = d0 * d0 + d1 * d1 + d2 * d2 + 1e-5f;
    float r = sqrtf(r2);
    float invr = 1.0f / r;

    // rbf: sin(n*theta) via Chebyshev recurrence, theta = pi*r/5
    float theta = r * 0.6283185307179586f;
    float s1, c1;
    __sincosf(theta, &s1, &c1);
    float c2 = 2.f * c1;
    float sn[L_DIM];
    sn[0] = s1;
    sn[1] = c2 * s1;
#pragma unroll
    for (int l = 2; l < L_DIM; l++) sn[l] = c2 * sn[l - 1] - sn[l - 2];

    us4 pv = phi4[(size_t)j * 128 + f];
    us4 vv = v4[(size_t)j * 128 + f];

    float m[3];
#pragma unroll
    for (int t = 0; t < 3; t++) {
      float dot = 0.f;
#pragma unroll
      for (int l = 0; l < L_DIM; l++) dot = fmaf(sn[l], mvw[t][l], dot);
      float wp = fmaf(dot, invr, mvw[t][20]);
      float w = 0.f;
      if (wp < 5.0f) w = 0.5f * (__cosf(wp * 0.6283185307179586f) + 1.0f);
      m[t] = w;
    }
    float m0 = bf2f(pv.x) * m[0];
    float m1 = bf2f(pv.y) * m[1];
    float m2 = bf2f(pv.z) * m[2];
    float rr = m2 * invr;
    accV0 = fmaf(bf2f(vv.x), m0, fmaf(rr, d0, accV0));
    accV1 = fmaf(bf2f(vv.y), m0, fmaf(rr, d1, accV1));
    accV2 = fmaf(bf2f(vv.z), m0, fmaf(rr, d2, accV2));
    accS += m1;
  }

  const int idx = half * 64 + lane;
  if (split == 1) {
    red[idx * 4 + 0] = accV0; red[idx * 4 + 1] = accV1;
    red[idx * 4 + 2] = accV2; red[idx * 4 + 3] = accS;
  }
  __syncthreads();
  if (split == 0) {
    accV0 += red[idx * 4 + 0]; accV1 += red[idx * 4 + 1];
    accV2 += red[idx * 4 + 2]; accS  += red[idx * 4 + 3];
    size_t b3 = (size_t)i * 384 + f * 3;
    float n0 = v[b3] + accV0, n1 = v[b3 + 1] + accV1, n2 = v[b3 + 2] + accV2;
    vnew[b3] = n0; vnew[b3 + 1] = n1; vnew[b3 + 2] = n2;
    us4 o; o.x = f2bf(n0); o.y = f2bf(n1); o.z = f2bf(n2); o.w = 0;
    vnew4[(size_t)i * 128 + f] = o;
    size_t b1 = (size_t)i * 128 + f;
    float sv = s[b1] + accS;
    snew[b1] = sv;
    snew_bf[b1] = f2bf(sv);
  }
}

// ---------------------------------------------------------------------------
// pass 2: block = 1 dst node, 4 waves = (feature half) x (edge parity).
__global__ __launch_bounds__(256, 8) void pass2_kernel(
    const float* __restrict__ vnew,   // [N,128,3] fp32
    const us4*  __restrict__ vnew4,   // [N,128] bf16 packed
    const float* __restrict__ snew,   // [N,128]
    const us4*  __restrict__ s2p,     // [N,128] bf16 packed {avv,asv,ass,_}
    const int* __restrict__ ebuf, const int* __restrict__ deg,
    float* __restrict__ vout, float* __restrict__ sout, int nNodes)
{
  __shared__ float red[1024];
  const int wave = threadIdx.x >> 6, lane = threadIdx.x & 63;
  const int half = wave >> 1, split = wave & 1;
  const int i = blockIdx.x;
  const int f = lane + 64 * half;

  int cnt = deg[i]; if (cnt > CAP) cnt = CAP;
  const int base = i * CAP;
  int jv = (lane < cnt) ? ebuf[base + lane] : 0;

  float accU0 = 0.f, accU1 = 0.f, accU2 = 0.f;
  float accM0 = 0.f, accM1 = 0.f, accM2 = 0.f;

#pragma unroll 2
  for (int e = split; e < cnt; e += 2) {
    int j = __shfl(jv, e);
    us4 sm = s2p[(size_t)j * 128 + f];
    us4 vm = vnew4[(size_t)j * 128 + f];
    accM0 += bf2f(sm.x); accM1 += bf2f(sm.y); accM2 += bf2f(sm.z);
    accU0 += bf2f(vm.x); accU1 += bf2f(vm.y); accU2 += bf2f(vm.z);
  }

  const int idx = half * 64 + lane;
  if (split == 1) {
    red[idx * 8 + 0] = accU0; red[idx * 8 + 1] = accU1; red[idx * 8 + 2] = accU2;
    red[idx * 8 + 3] = accM0; red[idx * 8 + 4] = accM1; red[idx * 8 + 5] = accM2;
  }
  __syncthreads();
  if (split == 0) {
    accU0 += red[idx * 8 + 0]; accU1 += red[idx * 8 + 1]; accU2 += red[idx * 8 + 2];
    accM0 += red[idx * 8 + 3]; accM1 += red[idx * 8 + 4]; accM2 += red[idx * 8 + 5];

    float dinv = 1.0f / (float)(cnt > 0 ? cnt : 1);
    float uv0 = accU0 * dinv, uv1 = accU1 * dinv, uv2 = accU2 * dinv;
    float avv = accM0 * dinv, asv = accM1 * dinv, ass = accM2 * dinv;
    float q = uv0 * uv0 + uv1 * uv1 + uv2 * uv2;
    float ds2 = (q / (q + 1e-5f)) * asv + ass;
    size_t b3 = (size_t)i * 384 + f * 3;
    vout[b3]     = vnew[b3]     + uv0 * avv;
    vout[b3 + 1] = vnew[b3 + 1] + uv1 * avv;
    vout[b3 + 2] = vnew[b3 + 2] + uv2 * avv;
    size_t b1 = (size_t)i * 128 + f;
    sout[b1] = snew[b1] + ds2;
  }
}

// ---------------------------------------------------------------------------
extern "C" void kernel_launch(void* const* d_in, const int* in_sizes, int n_in,
                              void* d_out, int out_size, void* d_ws, size_t ws_size,
                              hipStream_t stream)
{
  const float* x     = (const float*)d_in[0];
  const float* v     = (const float*)d_in[1];
  const float* s     = (const float*)d_in[2];
  const float* ms1_w = (const float*)d_in[3];
  const float* ms1_b = (const float*)d_in[4];
  const float* ms2_w = (const float*)d_in[5];
  const float* ms2_b = (const float*)d_in[6];
  const float* mv_w  = (const float*)d_in[7];
  const float* mv_b  = (const float*)d_in[8];
  const float* us1_w = (const float*)d_in[9];
  const float* us1_b = (const float*)d_in[10];
  const float* us2_w = (const float*)d_in[11];
  const float* us2_b = (const float*)d_in[12];
  const int*   src   = (const int*)d_in[13];
  const int*   dst   = (const int*)d_in[14];

  const int N = in_sizes[0] / 3;        // 10000
  const int E = in_sizes[13];           // 100000

  char* p = (char*)d_ws;
  auto alloc = [&](size_t bytes) -> void* {
    void* r = (void*)p;
    p += (bytes + 255) & ~(size_t)255;
    return r;
  };
  unsigned short* sbf   = (unsigned short*)alloc((size_t)N * 128 * 2);
  unsigned short* snbf  = (unsigned short*)alloc((size_t)N * 128 * 2);
  unsigned short* w_ms1 = (unsigned short*)alloc(16384 * 2);
  unsigned short* w_ms2 = (unsigned short*)alloc(49152 * 2);
  unsigned short* w_us1 = (unsigned short*)alloc(16384 * 2);
  unsigned short* w_us2 = (unsigned short*)alloc(49152 * 2);
  float* mvp    = (float*)alloc(384 * 24 * 4);
  us4*   phi4   = (us4*)alloc((size_t)N * 128 * 8);     // phi, then s2 (reused)
  us4*   v4     = (us4*)alloc((size_t)N * 128 * 8);
  us4*   vnew4  = (us4*)alloc((size_t)N * 128 * 8);
  float* vnew   = (float*)alloc((size_t)N * 384 * 4);
  float* snew   = (float*)alloc((size_t)N * 128 * 4);
  int* cursor   = (int*)alloc((size_t)N * 4);           // becomes deg after fill
  int* ebuf     = (int*)alloc((size_t)N * CAP * 4);

  hipMemsetAsync(cursor, 0, (size_t)N * 4, stream);

  cast_kernel<<<(N * 128 + 255) / 256, 256, 0, stream>>>(
      ms1_w, w_ms1, ms2_w, w_ms2, us1_w, w_us1, us2_w, w_us2,
      s, sbf, v, v4, mv_w, mv_b, mvp, N * 128);

  fill_kernel<<<(E + 255) / 256, 256, 0, stream>>>(src, dst, cursor, ebuf, E);

  // phi = ssp(s @ ms1^T + b) @ ms2^T + b   (packed bf16 out)
  mlp_kernel<<<N / 16, 64, 0, stream>>>(sbf, w_ms1, ms1_b, w_ms2, ms2_b,
                                        (unsigned short*)phi4);

  pass1_kernel<<<N, 256, 0, stream>>>(x, v4, v, s, phi4, mvp,
                                      ebuf, cursor, vnew, vnew4, snew, snbf, N);

  // s2 = ssp(s_new @ us1^T + b) @ us2^T + b   (packed bf16 out, reuses phi4)
  mlp_kernel<<<N / 16, 64, 0, stream>>>(snbf, w_us1, us1_b, w_us2, us2_b,
                                        (unsigned short*)phi4);

  float* vout = (float*)d_out;
  float* sout = vout + (size_t)N * 384;
  pass2_kernel<<<N, 256, 0, stream>>>(vnew, vnew4, snew, phi4, ebuf, cursor,
                                      vout, sout, N);
}